// Round 1
// 480.916 us; speedup vs baseline: 1.1115x; 1.1115x over previous
//
#include <hip/hip_runtime.h>
#include <hip/hip_bf16.h>

#define B_ 4
#define D_ 64
#define N_ 16
#define HW_ 4096

#define LDSA 72
#define LDSB 66

// workspace offsets (bytes)
#define OFF_D2    0u
#define OFF_ATAB  8192u
#define OFF_MEAN  12288u
#define OFF_RSTD  12352u
#define OFF_PART  12416u
#define OFF_W9    16384u
#define OFF_UNT   131072u
#define OFF_DELTA 2228224u
#define OFF_BVAL  6422528u
#define OFF_CVAL  7471104u

typedef __bf16 v8bf __attribute__((ext_vector_type(8)));
typedef float  v4f  __attribute__((ext_vector_type(4)));

__device__ __forceinline__ unsigned short f2bf(float f){
  __hip_bfloat16 h = __float2bfloat16(f);
  return *reinterpret_cast<unsigned short*>(&h);
}
__device__ __forceinline__ v8bf ld8bf(const unsigned short* p){
  union{uint4 u; v8bf v;} c; c.u = *(const uint4*)p; return c.v;
}

// ---------------- init: spectral-derivative table + A = -exp(logA) ----------
__global__ void k_init(const float* __restrict__ logA,
                       unsigned short* __restrict__ D2w, float* __restrict__ Atab){
  int g = blockIdx.x*256 + threadIdx.x;
  if(g < 4096){
    int r = g>>6, m = g&63;
    int p = (r - m) & 63;
    float s = 0.f;
    for(int k=1;k<32;k++) s += (float)k * sinf(0.09817477042468103f * (float)(k*p));
    D2w[g] = f2bf(-0.0030679615757712823f * s);
  } else if(g < 5120){
    int idx = g - 4096;
    Atab[idx] = -__expf(logA[idx]);
  }
}

// ---------------- repack conv weights to [tap][co(96)][ci(64)] bf16 ---------
__global__ void k_wrepack(const float* __restrict__ wd,
                          const float* __restrict__ wB,
                          const float* __restrict__ wC,
                          unsigned short* __restrict__ W9){
  int idx = blockIdx.x*256 + threadIdx.x;   // 0..6143
  if(idx >= 96*64) return;
  int co = idx>>6, ci = idx&63;
  const float* src;
  if(co < 64)      src = wd + ((size_t)co*64 + ci)*9;
  else if(co < 80) src = wB + ((size_t)(co-64)*64 + ci)*9;
  else             src = wC + ((size_t)(co-80)*64 + ci)*9;
  for(int tap=0; tap<9; tap++)
    W9[((size_t)tap*96 + co)*64 + ci] = f2bf(src[tap]);
}

// ---------------- GroupNorm statistics, stage 1: 256 partial blocks ---------
__global__ void k_gn1(const float* __restrict__ u, float* __restrict__ part){
  int bid = blockIdx.x;                      // bg*16 + sub
  const float* base = u + (size_t)(bid>>4)*65536 + (size_t)(bid&15)*4096;
  int t = threadIdx.x;                       // 0..255
  float s=0.f, s2=0.f;
  #pragma unroll
  for(int j=0;j<4;j++){
    float4 v = ((const float4*)base)[t + 256*j];
    s  += v.x+v.y+v.z+v.w;
    s2 += v.x*v.x+v.y*v.y+v.z*v.z+v.w*v.w;
  }
  #pragma unroll
  for(int o=32;o>0;o>>=1){ s += __shfl_down(s,o); s2 += __shfl_down(s2,o); }
  __shared__ float ls[4], ls2[4];
  int wv = t>>6;
  if((t&63)==0){ ls[wv]=s; ls2[wv]=s2; }
  __syncthreads();
  if(t==0){
    part[bid]       = ls[0]+ls[1]+ls[2]+ls[3];
    part[256 + bid] = ls2[0]+ls2[1]+ls2[2]+ls2[3];
  }
}

// ---------------- GroupNorm statistics, stage 2: finalize 16 groups ---------
__global__ void k_gn2(const float* __restrict__ part,
                      float* __restrict__ meanw, float* __restrict__ rstdw){
  int t = threadIdx.x;
  if(t < 16){
    float S=0.f, S2=0.f;
    for(int i=0;i<16;i++){ S += part[t*16+i]; S2 += part[256 + t*16+i]; }
    float mu = S/65536.f;
    float var = S2/65536.f - mu*mu;
    meanw[t]=mu; rstdw[t]=rsqrtf(var+1e-5f);
  }
}

// ---------------- apply GN + transpose to unT[b][pixel][ci] (bf16) ----------
__global__ __launch_bounds__(512) void k_unT(
    const float* __restrict__ u_t,
    const float* __restrict__ meanw, const float* __restrict__ rstdw,
    const float* __restrict__ gamma, const float* __restrict__ beta,
    unsigned short* __restrict__ unT){
  __shared__ unsigned short T[64*LDSA];
  int bid = blockIdx.x;
  int b = bid>>6, h = bid&63;
  int t = threadIdx.x;                 // 0..511
  int w = t&63, cg = t>>6;             // cg = wave 0..7
  #pragma unroll
  for(int i=0;i<8;i++){
    int c = cg*8 + i;
    float x = u_t[(((size_t)b*64 + c)*64 + h)*64 + w];
    int g = c>>4;
    float v = (x - meanw[b*4+g])*rstdw[b*4+g]*gamma[c] + beta[c];
    T[w*LDSA + c] = f2bf(v);
  }
  __syncthreads();
  int w2 = t>>3, cq = t&7;             // 64 pixels x 8 ci-octets
  uint4 v0 = *(uint4*)&T[w2*LDSA + cq*8];
  uint4* dst = (uint4*)(unT + ((size_t)b*HW_ + h*64 + w2)*64 + cq*8);
  dst[0] = v0;
}

// ---------------- conv as 9 shifted GEMMs via MFMA (co-group split) ---------
__global__ __launch_bounds__(256) void k_conv(
    const unsigned short* __restrict__ unT,
    const unsigned short* __restrict__ W9,
    const float* __restrict__ b_d,
    const float* __restrict__ dtp,
    float* __restrict__ deltaw, float* __restrict__ Bvalw, float* __restrict__ Cvalw){
  int bid = blockIdx.x;
  int cg = bid >> 8;                   // 0..2  (co group of 32)
  int b = (bid>>6) & 3, h = bid & 63;
  int t = threadIdx.x;
  int wv = t>>6, l = t&63;
  int lr = l&15, lk = l>>4;
  v4f acc[2];
  acc[0] = (v4f){0.f,0.f,0.f,0.f};
  acc[1] = (v4f){0.f,0.f,0.f,0.f};
  int wpix = wv*16 + lr;
  #pragma unroll
  for(int tap=0; tap<9; tap++){
    int dy = tap/3 - 1, dx = tap - (tap/3)*3 - 1;
    int hh = (h+dy)&63;
    int ww = (wpix+dx)&63;
    const unsigned short* bp = unT + ((size_t)b*HW_ + hh*64 + ww)*64;
    const unsigned short* ap = W9 + (size_t)tap*96*64 + (size_t)cg*32*64;
    #pragma unroll
    for(int ks=0; ks<2; ks++){
      int k0 = ks*32 + lk*8;
      v8bf bfrag = ld8bf(bp + k0);
      #pragma unroll
      for(int m2=0; m2<2; m2++){
        v8bf afrag = ld8bf(ap + (m2*16+lr)*64 + k0);
        acc[m2] = __builtin_amdgcn_mfma_f32_16x16x32_bf16(afrag, bfrag, acc[m2], 0,0,0);
      }
    }
  }
  float dt = dtp[0];
  int p = h*64 + wpix;
  #pragma unroll
  for(int m2=0; m2<2; m2++){
    #pragma unroll
    for(int r=0;r<4;r++){
      int co = cg*32 + m2*16 + lk*4 + r;
      float v = acc[m2][r];
      if(co < 64){
        float x = v + b_d[co] + dt;
        float sp = (x > 15.f) ? x : log1pf(__expf(x));
        sp = fminf(fmaxf(sp, 1e-4f), 5.f);
        deltaw[((size_t)b*64 + co)*HW_ + p] = sp;
      } else if(co < 80){
        Bvalw[((size_t)b*16 + (co-64))*HW_ + p] = v;
      } else {
        Cvalw[((size_t)b*16 + (co-80))*HW_ + p] = v;
      }
    }
  }
}

// ---------------- fused spectral-grad + state update: one (b,d,n) per block -
__global__ __launch_bounds__(256) void k_main(
    const float* __restrict__ u_t,
    const float* __restrict__ s_prev,
    const unsigned short* __restrict__ D2w,
    const float* __restrict__ Atab,
    const float* __restrict__ deltaw,
    const float* __restrict__ Bvalw,
    float* __restrict__ out_s){
  __shared__ unsigned short D2s[64*LDSA];
  __shared__ unsigned short Ms72[64*LDSA];
  __shared__ unsigned short Ms66[64*LDSB];

  // bijective XCD swizzle: co-locate the 16 n-planes of one (b,d) on one XCD
  int bid = blockIdx.x;
  int lid = (bid & 7)*512 + (bid >> 3);
  int n  = lid & 15;
  int d  = (lid>>4) & 63;
  int b  = lid >> 10;
  int t = threadIdx.x;
  int wv = t>>6, l = t&63;
  int lr = l & 15, lk = l >> 4;
  int r0 = wv*16;

  const size_t PL = (size_t)D_*N_*HW_;
  size_t bd = (size_t)b*64 + d;
  size_t sbase = (size_t)b*3*PL + (size_t)d*(N_*HW_) + (size_t)n*HW_;
  const float* m0p = s_prev + sbase;
  const float* mxp = m0p + PL;
  const float* myp = m0p + 2*PL;
  float* so = out_s + sbase;
  const float* up = u_t + bd*HW_;
  const float* dp = deltaw + bd*HW_;
  const float* Bp = Bvalw + ((size_t)b*16 + n)*HW_;

  // stage D2 table (8 KB, L2-hot)
  #pragma unroll
  for(int j=0;j<2;j++){
    int chunk = t + 256*j;           // 0..511 uint4 chunks
    int r = chunk>>3, cb = chunk&7;
    uint4 v = ((const uint4*)D2w)[chunk];
    *(uint4*)&D2s[r*LDSA + cb*8] = v;
  }

  // stage m0 (fp32 -> bf16) into both LDS layouts
  #pragma unroll
  for(int j=0;j<4;j++){
    int chunk = t + 256*j;           // 0..1023 float4 chunks
    int r = chunk>>4, cb = chunk&15;
    float4 v = ((const float4*)m0p)[chunk];
    unsigned int lo = (unsigned int)f2bf(v.x) | ((unsigned int)f2bf(v.y)<<16);
    unsigned int hi = (unsigned int)f2bf(v.z) | ((unsigned int)f2bf(v.w)<<16);
    unsigned int* d72 = (unsigned int*)&Ms72[r*LDSA + cb*4];
    d72[0]=lo; d72[1]=hi;
    unsigned int* d66 = (unsigned int*)&Ms66[r*LDSB + cb*4];
    d66[0]=lo; d66[1]=hi;
  }
  __syncthreads();

  float An = Atab[d*16 + n];

  #pragma unroll
  for(int ct=0; ct<4; ct++){
    v4f gx = {0.f,0.f,0.f,0.f}, gy = {0.f,0.f,0.f,0.f};
    #pragma unroll
    for(int ks=0; ks<2; ks++){
      int k0 = ks*32 + lk*8;
      // grad_x = M * D2^T : A = M rows (r0..r0+15), B[k][n]=D2[col n][k]
      v8bf a_gx = ld8bf(&Ms72[(r0+lr)*LDSA + k0]);
      v8bf b_gx = ld8bf(&D2s[(ct*16+lr)*LDSA + k0]);
      gx = __builtin_amdgcn_mfma_f32_16x16x32_bf16(a_gx, b_gx, gx, 0,0,0);
      // grad_y = D2 * M : A = D2 rows, B[k=m][n] = M[m][col n] (strided u16)
      v8bf a_gy = ld8bf(&D2s[(r0+lr)*LDSA + k0]);
      union { unsigned short s[8]; v8bf v; } bg;
      #pragma unroll
      for(int i=0;i<8;i++) bg.s[i] = Ms66[(k0+i)*LDSB + ct*16 + lr];
      gy = __builtin_amdgcn_mfma_f32_16x16x32_bf16(a_gy, bg.v, gy, 0,0,0);
    }
    #pragma unroll
    for(int r=0;r<4;r++){
      int p = (r0 + lk*4 + r)*64 + ct*16 + lr;
      float m0 = m0p[p];
      float mx = mxp[p];
      float my = myp[p];
      float dv = dp[p];
      float uu = up[p];
      float ab = __expf(dv*An);
      float m0n = ab*m0 + dv*Bp[p]*uu;
      so[p]        = m0n;
      so[PL + p]   = ab*(mx - gx[r]);
      so[2*PL + p] = ab*(my - gy[r]);
    }
  }
}

// ---------------- y epilogue: y = sum_n m0_new*C + u*D_param ----------------
__global__ void k_y(const float* __restrict__ m0new,    // = out_s base
                    const float* __restrict__ Cvalw,
                    const float* __restrict__ u_t,
                    const float* __restrict__ Dp,
                    float* __restrict__ out_y){
  int i = blockIdx.x*256 + threadIdx.x;   // 0..262143 float4s
  int b = i>>16;
  int d = (i>>10)&63;
  int pq = i & 1023;
  const size_t PL = (size_t)D_*N_*HW_;
  float Dv = Dp[d];
  const float4* m0b = (const float4*)(m0new + (size_t)b*3*PL + (size_t)d*(N_*HW_)) + pq;
  const float4* Cb  = (const float4*)Cvalw + (size_t)b*16*1024 + pq;
  float4 acc = {0.f,0.f,0.f,0.f};
  #pragma unroll
  for(int n=0;n<16;n++){
    float4 m = m0b[(size_t)n*1024];
    float4 c = Cb[(size_t)n*1024];
    acc.x += m.x*c.x; acc.y += m.y*c.y; acc.z += m.z*c.z; acc.w += m.w*c.w;
  }
  float4 uv = ((const float4*)u_t)[i];
  float4 o;
  o.x = acc.x + uv.x*Dv;
  o.y = acc.y + uv.y*Dv;
  o.z = acc.z + uv.z*Dv;
  o.w = acc.w + uv.w*Dv;
  ((float4*)out_y)[i] = o;
}

extern "C" void kernel_launch(void* const* d_in, const int* in_sizes, int n_in,
                              void* d_out, int out_size, void* d_ws, size_t ws_size,
                              hipStream_t stream){
  const float* u_t    = (const float*)d_in[0];
  const float* s_prev = (const float*)d_in[1];
  const float* gamma  = (const float*)d_in[2];
  const float* beta   = (const float*)d_in[3];
  const float* w_d    = (const float*)d_in[4];
  const float* b_d    = (const float*)d_in[5];
  const float* w_B    = (const float*)d_in[6];
  const float* w_C    = (const float*)d_in[7];
  const float* logA   = (const float*)d_in[8];
  const float* Dp     = (const float*)d_in[9];
  const float* dtp    = (const float*)d_in[10];

  char* ws = (char*)d_ws;
  unsigned short* D2w  = (unsigned short*)(ws + OFF_D2);
  float* Atab          = (float*)(ws + OFF_ATAB);
  float* meanw         = (float*)(ws + OFF_MEAN);
  float* rstdw         = (float*)(ws + OFF_RSTD);
  float* part          = (float*)(ws + OFF_PART);
  unsigned short* W9   = (unsigned short*)(ws + OFF_W9);
  unsigned short* unT  = (unsigned short*)(ws + OFF_UNT);
  float* deltaw        = (float*)(ws + OFF_DELTA);
  float* Bvalw         = (float*)(ws + OFF_BVAL);
  float* Cvalw         = (float*)(ws + OFF_CVAL);

  float* out_y = (float*)d_out;
  float* out_s = out_y + 1048576;

  k_init   <<<20, 256, 0, stream>>>(logA, D2w, Atab);
  k_wrepack<<<24, 256, 0, stream>>>(w_d, w_B, w_C, W9);
  k_gn1    <<<256, 256, 0, stream>>>(u_t, part);
  k_gn2    <<<1, 64, 0, stream>>>(part, meanw, rstdw);
  k_unT    <<<256, 512, 0, stream>>>(u_t, meanw, rstdw, gamma, beta, unT);
  k_conv   <<<768, 256, 0, stream>>>(unT, W9, b_d, dtp, deltaw, Bvalw, Cvalw);
  k_main   <<<4096, 256, 0, stream>>>(u_t, s_prev, D2w, Atab, deltaw, Bvalw, out_s);
  k_y      <<<1024, 256, 0, stream>>>(out_s, Cvalw, u_t, Dp, out_y);
}